// Round 10
// baseline (146.283 us; speedup 1.0000x reference)
//
#include <hip/hip_runtime.h>
#include <hip/hip_bf16.h>
#include <cstdint>

#define HASH_SIZE (1u<<19)
#define NPTS 262144
#define DENS_N 2097152

typedef unsigned short u16;
typedef u16 u16x8 __attribute__((ext_vector_type(8)));
typedef __bf16 bf16x8 __attribute__((ext_vector_type(8)));
typedef float f32x4 __attribute__((ext_vector_type(4)));

__device__ __forceinline__ u16 f2bf(float f){
  uint32_t u = __builtin_bit_cast(uint32_t, f);
  u += 0x7fffu + ((u>>16)&1u);       // RNE; inputs are finite
  return (u16)(u>>16);
}
__device__ __forceinline__ float bf2f(u16 s){
  uint32_t u = ((uint32_t)s)<<16;
  return __builtin_bit_cast(float, u);
}

// W1 [512][64] f32 -> W1T [64][512] bf16 with the K-dim PERMUTED inside each
// 32-wide level chunk so each gather instruction touches ONE contiguous 64B
// sector per row:  k_mfma = kg*8+j  holds  k_orig = (j>>2)*16 + kg*4 + (j&3).
// A-fragment uses the same permutation -> dot product unchanged.
// W2 [64][64] f32 -> W2T [64][64] bf16 (unpermuted).
__global__ void prep_weights(const float* __restrict__ W1, const float* __restrict__ W2,
                             u16* __restrict__ W1T, u16* __restrict__ W2T){
  int t = blockIdx.x*blockDim.x + threadIdx.x;
  int stride = gridDim.x*blockDim.x;
  for (int i=t; i<64*512; i+=stride){
    int o = i>>9, k = i&511;
    int s = k>>5, km = k&31, kg = km>>3, j = km&7;
    int k_orig = ((j>>2)<<4) + (kg<<2) + (j&3);
    W1T[i] = f2bf(W1[((s<<5) + k_orig)*64 + o]);
  }
  for (int i=t; i<64*64;  i+=stride){ int o=i>>6, k=i&63;  W2T[i] = f2bf(W2[k*64+o]); }
}

__global__ void density_sigmoid(const float4* __restrict__ in, float4* __restrict__ out){
  int i = blockIdx.x*blockDim.x + threadIdx.x;   // exactly 524288 threads
  float4 v = in[i];
  v.x = 1.f/(1.f+__expf(-v.x));
  v.y = 1.f/(1.f+__expf(-v.y));
  v.z = 1.f/(1.f+__expf(-v.z));
  v.w = 1.f/(1.f+__expf(-v.w));
  out[i] = v;
}

// 512 threads = 8 independent waves, 16 points each (128 pts/block).
// LDS = w1s(64K) + hbuf(16K) = 80 KiB -> TWO blocks co-resident per CU; one
// block's compute phase overlaps the other's gather wait (the CU-idle wall).
// W2T (8 KB, read-only) is read from global and stays L1-resident, shared by
// both blocks.
__global__ void __launch_bounds__(512, 4) fused_mlp(
    const float* __restrict__ xyz, const float* __restrict__ fg,
    const u16* __restrict__ W1T, const u16* __restrict__ W2T,
    const float* __restrict__ b1, const float* __restrict__ b2,
    const float* __restrict__ W3, const float* __restrict__ b3,
    float* __restrict__ color)
{
  __shared__ u16 w1s[64*512];      // 64 KiB, granule-swizzled
  __shared__ u16 hbuf[8][16*64];   // 16 KiB; h1 then h2 in place (same-wave)

  const int t = threadIdx.x;
  const int wave = t >> 6;
  const int lane = t & 63;
  const int p  = lane & 15;            // point within this wave's 16-point tile
  const int kg = lane >> 4;            // k-subgroup 0..3
  const int gp = (blockIdx.x << 7) + (wave << 4) + p;   // global point id

  // ---- issue gather loads FIRST (misses start early; 32 in flight/wave) ----
  const float x = xyz[gp*3+0];
  const float y = xyz[gp*3+1];
  const float z = xyz[gp*3+2];
  f32x4 a0[16], a1[16];
  #pragma unroll
  for (int s=0; s<16; ++s){
    const float resf = (float)(16 << s);
    uint32_t ix = (uint32_t)(x*resf);
    uint32_t iy = (uint32_t)(y*resf);
    uint32_t iz = (uint32_t)(z*resf);
    uint32_t h = (ix ^ (iy*2654435761u) ^ (iz*805459861u)) & (HASH_SIZE-1u);
    const float* ap = fg + (size_t)((((uint32_t)s<<19) | h) * 32u);
    a0[s] = *(const f32x4*)(ap + (kg<<2));          // bytes [kg*16, kg*16+16)
    a1[s] = *(const f32x4*)(ap + 16 + (kg<<2));     // bytes [64+kg*16, ...)
  }

  // ---- stage W1T into LDS (cooperative, swizzled granules of 16 B) ----
  // w1s: granule (col, g) g=0..63 stored at col*512 + (g ^ (col&7))*8 (u16 units)
  #pragma unroll
  for (int i=0; i<8; ++i){
    int g = t + (i<<9);                 // 512 threads x 8 = 4096 granules
    int col = g >> 6, gr = g & 63;
    u16x8 v = *(const u16x8*)(W1T + (g<<3));
    *(u16x8*)(w1s + (col<<9) + (((gr) ^ (col&7))<<3)) = v;
  }
  __syncthreads();

  // ---- GEMM1: features @ W1 -> h1 [16 x 64] ----
  f32x4 acc[4];
  #pragma unroll
  for (int tt=0; tt<4; ++tt) acc[tt] = (f32x4){0.f,0.f,0.f,0.f};

  #pragma unroll
  for (int s=0; s<16; ++s){
    bf16x8 ab = { (__bf16)a0[s][0], (__bf16)a0[s][1], (__bf16)a0[s][2], (__bf16)a0[s][3],
                  (__bf16)a1[s][0], (__bf16)a1[s][1], (__bf16)a1[s][2], (__bf16)a1[s][3] };
    #pragma unroll
    for (int tt=0; tt<4; ++tt){
      const int col = (lane&15) + (tt<<4);
      u16x8 bu = *(const u16x8*)(w1s + (col<<9) + ((((s<<2)+kg) ^ (col&7))<<3));
      acc[tt] = __builtin_amdgcn_mfma_f32_16x16x32_bf16(
          ab, __builtin_bit_cast(bf16x8, bu), acc[tt], 0,0,0);
    }
  }
  #pragma unroll
  for (int tt=0; tt<4; ++tt){
    const int col = (lane&15) + (tt<<4);
    const float bias = b1[col];
    #pragma unroll
    for (int r=0; r<4; ++r){
      const int row = (kg<<2) + r;        // C row = point within tile
      float v = acc[tt][r] + bias;
      v = v > 0.f ? v : 0.f;
      hbuf[wave][(row*64 + col) ^ ((row&7)<<3)] = f2bf(v);  // XOR-swizzled
    }
  }

  // ---- GEMM2: h1 @ W2 -> h2 [16 x 64] ---- (same-wave LDS deps; no barrier)
  // B-fragments straight from global W2T: 8 KB read-only, L1-resident.
  f32x4 acc2[4];
  #pragma unroll
  for (int tt=0; tt<4; ++tt) acc2[tt] = (f32x4){0.f,0.f,0.f,0.f};

  #pragma unroll
  for (int kc=0; kc<2; ++kc){
    const int aidx = (p*64 + kc*32 + kg*8) ^ ((p&7)<<3);
    u16x8 au = *(const u16x8*)(&hbuf[wave][aidx]);
    bf16x8 ab = __builtin_bit_cast(bf16x8, au);
    #pragma unroll
    for (int tt=0; tt<4; ++tt){
      const int col = (lane&15) + (tt<<4);
      u16x8 bu = *(const u16x8*)(W2T + (col<<6) + (kc<<5) + (kg<<3));
      acc2[tt] = __builtin_amdgcn_mfma_f32_16x16x32_bf16(
          ab, __builtin_bit_cast(bf16x8, bu), acc2[tt], 0,0,0);
    }
  }
  // overwrite h1 with h2 in place: all h1 reads (above) precede these writes
  // in this wave's program order; LDS ops within a wave execute in order.
  #pragma unroll
  for (int tt=0; tt<4; ++tt){
    const int col = (lane&15) + (tt<<4);
    const float bias = b2[col];
    #pragma unroll
    for (int r=0; r<4; ++r){
      const int row = (kg<<2) + r;
      float v = acc2[tt][r] + bias;
      v = v > 0.f ? v : 0.f;
      hbuf[wave][(row*64 + col) ^ ((row&7)<<3)] = f2bf(v);
    }
  }

  // ---- layer 3: [16 x 64] @ [64 x 3] + sigmoid ----
  if (lane < 48){
    const int pp = lane / 3, c = lane % 3;
    float sum = b3[c];
    #pragma unroll
    for (int o=0; o<64; ++o){
      sum += bf2f(hbuf[wave][(pp*64+o) ^ ((pp&7)<<3)]) * W3[o*3+c];
    }
    const int gpp = (blockIdx.x << 7) + (wave << 4) + pp;
    color[(size_t)gpp*3 + c] = 1.f/(1.f+__expf(-sum));
  }
}

extern "C" void kernel_launch(void* const* d_in, const int* in_sizes, int n_in,
                              void* d_out, int out_size, void* d_ws, size_t ws_size,
                              hipStream_t stream){
  const float* xyz  = (const float*)d_in[0];
  const float* fg   = (const float*)d_in[1];
  const float* dens = (const float*)d_in[2];
  const float* W1   = (const float*)d_in[3];
  const float* b1   = (const float*)d_in[4];
  const float* W2   = (const float*)d_in[5];
  const float* b2   = (const float*)d_in[6];
  const float* W3   = (const float*)d_in[7];
  const float* b3   = (const float*)d_in[8];
  float* out = (float*)d_out;

  u16* W1T = (u16*)d_ws;            // 64*512*2 = 64 KiB
  u16* W2T = W1T + 64*512;          // 64*64*2  =  8 KiB

  hipLaunchKernelGGL(prep_weights, dim3(64), dim3(256), 0, stream, W1, W2, W1T, W2T);
  hipLaunchKernelGGL(density_sigmoid, dim3(DENS_N/1024), dim3(256), 0, stream,
                     (const float4*)dens, (float4*)out);
  hipLaunchKernelGGL(fused_mlp, dim3(NPTS/128), dim3(512), 0, stream,
                     xyz, fg, W1T, W2T, b1, b2, W3, b3, out + DENS_N);
}

// Round 11
// 129.482 us; speedup vs baseline: 1.1298x; 1.1298x over previous
//
#include <hip/hip_runtime.h>
#include <hip/hip_bf16.h>
#include <cstdint>

#define HASH_SIZE (1u<<19)
#define NPTS 262144
#define DENS_N 2097152

typedef unsigned short u16;
typedef u16 u16x8 __attribute__((ext_vector_type(8)));
typedef __bf16 bf16x8 __attribute__((ext_vector_type(8)));
typedef float f32x4 __attribute__((ext_vector_type(4)));

__device__ __forceinline__ u16 f2bf(float f){
  uint32_t u = __builtin_bit_cast(uint32_t, f);
  u += 0x7fffu + ((u>>16)&1u);       // RNE; inputs are finite
  return (u16)(u>>16);
}
__device__ __forceinline__ float bf2f(u16 s){
  uint32_t u = ((uint32_t)s)<<16;
  return __builtin_bit_cast(float, u);
}

// W1 [512][64] f32 -> W1T [64][512] bf16 with the K-dim PERMUTED inside each
// 32-wide level chunk so each gather instruction touches ONE contiguous 64B
// sector per row:  k_mfma = kg*8+j  holds  k_orig = (j>>2)*16 + kg*4 + (j&3).
// A-fragment uses the same permutation -> dot product unchanged.
// W2 [64][64] f32 -> W2T [64][64] bf16 (unpermuted).
__global__ void prep_weights(const float* __restrict__ W1, const float* __restrict__ W2,
                             u16* __restrict__ W1T, u16* __restrict__ W2T){
  int t = blockIdx.x*blockDim.x + threadIdx.x;
  int stride = gridDim.x*blockDim.x;
  for (int i=t; i<64*512; i+=stride){
    int o = i>>9, k = i&511;
    int s = k>>5, km = k&31, kg = km>>3, j = km&7;
    int k_orig = ((j>>2)<<4) + (kg<<2) + (j&3);
    W1T[i] = f2bf(W1[((s<<5) + k_orig)*64 + o]);
  }
  for (int i=t; i<64*64;  i+=stride){ int o=i>>6, k=i&63;  W2T[i] = f2bf(W2[k*64+o]); }
}

__global__ void density_sigmoid(const float4* __restrict__ in, float4* __restrict__ out){
  int i = blockIdx.x*blockDim.x + threadIdx.x;   // exactly 524288 threads
  float4 v = in[i];
  v.x = 1.f/(1.f+__expf(-v.x));
  v.y = 1.f/(1.f+__expf(-v.y));
  v.z = 1.f/(1.f+__expf(-v.z));
  v.w = 1.f/(1.f+__expf(-v.w));
  out[i] = v;
}

// 512 threads = 8 independent waves, 16 points each (128 pts/block).
// W1T+W2T staged in LDS (R5 structure). Gather lane layout is K-permuted so
// each dwordx4 instruction's per-row footprint is one contiguous 64B sector.
// This is the measured-best configuration (R5/R9, 129.6 us): every attempted
// deviation (batching, pipelining, nt, sc0, 2-blocks/CU) was neutral or worse.
__global__ void __launch_bounds__(512) fused_mlp(
    const float* __restrict__ xyz, const float* __restrict__ fg,
    const u16* __restrict__ W1T, const u16* __restrict__ W2T,
    const float* __restrict__ b1, const float* __restrict__ b2,
    const float* __restrict__ W3, const float* __restrict__ b3,
    float* __restrict__ color)
{
  __shared__ u16 w1s[64*512];      // 64 KiB, granule-swizzled
  __shared__ u16 w2s[64*64];       // 8 KiB, granule-swizzled
  __shared__ u16 hbuf[8][16*64];   // 16 KiB; h1 then h2 in place (same-wave)

  const int t = threadIdx.x;
  const int wave = t >> 6;
  const int lane = t & 63;
  const int p  = lane & 15;            // point within this wave's 16-point tile
  const int kg = lane >> 4;            // k-subgroup 0..3
  const int gp = (blockIdx.x << 7) + (wave << 4) + p;   // global point id

  // ---- issue gather loads FIRST (misses start early; 32 in flight/wave) ----
  const float x = xyz[gp*3+0];
  const float y = xyz[gp*3+1];
  const float z = xyz[gp*3+2];
  f32x4 a0[16], a1[16];
  #pragma unroll
  for (int s=0; s<16; ++s){
    const float resf = (float)(16 << s);
    uint32_t ix = (uint32_t)(x*resf);
    uint32_t iy = (uint32_t)(y*resf);
    uint32_t iz = (uint32_t)(z*resf);
    uint32_t h = (ix ^ (iy*2654435761u) ^ (iz*805459861u)) & (HASH_SIZE-1u);
    const float* ap = fg + (size_t)((((uint32_t)s<<19) | h) * 32u);
    a0[s] = *(const f32x4*)(ap + (kg<<2));          // bytes [kg*16, kg*16+16)
    a1[s] = *(const f32x4*)(ap + 16 + (kg<<2));     // bytes [64+kg*16, ...)
  }

  // ---- stage W1T/W2T into LDS (cooperative, swizzled granules of 16 B) ----
  // w1s: granule (col, g) g=0..63 stored at col*512 + (g ^ (col&7))*8 (u16 units)
  #pragma unroll
  for (int i=0; i<8; ++i){
    int g = t + (i<<9);                 // 512 threads x 8 = 4096 granules
    int col = g >> 6, gr = g & 63;
    u16x8 v = *(const u16x8*)(W1T + (g<<3));
    *(u16x8*)(w1s + (col<<9) + (((gr) ^ (col&7))<<3)) = v;
  }
  {
    int g = t;                           // 512 granules
    int col = g >> 3, gr = g & 7;
    u16x8 v = *(const u16x8*)(W2T + (g<<3));
    *(u16x8*)(w2s + (col<<6) + (((gr) ^ (col&7))<<3)) = v;
  }
  __syncthreads();

  // ---- GEMM1: features @ W1 -> h1 [16 x 64] ----
  f32x4 acc[4];
  #pragma unroll
  for (int tt=0; tt<4; ++tt) acc[tt] = (f32x4){0.f,0.f,0.f,0.f};

  #pragma unroll
  for (int s=0; s<16; ++s){
    bf16x8 ab = { (__bf16)a0[s][0], (__bf16)a0[s][1], (__bf16)a0[s][2], (__bf16)a0[s][3],
                  (__bf16)a1[s][0], (__bf16)a1[s][1], (__bf16)a1[s][2], (__bf16)a1[s][3] };
    #pragma unroll
    for (int tt=0; tt<4; ++tt){
      const int col = (lane&15) + (tt<<4);
      u16x8 bu = *(const u16x8*)(w1s + (col<<9) + ((((s<<2)+kg) ^ (col&7))<<3));
      acc[tt] = __builtin_amdgcn_mfma_f32_16x16x32_bf16(
          ab, __builtin_bit_cast(bf16x8, bu), acc[tt], 0,0,0);
    }
  }
  #pragma unroll
  for (int tt=0; tt<4; ++tt){
    const int col = (lane&15) + (tt<<4);
    const float bias = b1[col];
    #pragma unroll
    for (int r=0; r<4; ++r){
      const int row = (kg<<2) + r;        // C row = point within tile
      float v = acc[tt][r] + bias;
      v = v > 0.f ? v : 0.f;
      hbuf[wave][(row*64 + col) ^ ((row&7)<<3)] = f2bf(v);  // XOR-swizzled
    }
  }

  // ---- GEMM2: h1 @ W2 -> h2 [16 x 64] ---- (same-wave LDS deps; no barrier)
  f32x4 acc2[4];
  #pragma unroll
  for (int tt=0; tt<4; ++tt) acc2[tt] = (f32x4){0.f,0.f,0.f,0.f};

  #pragma unroll
  for (int kc=0; kc<2; ++kc){
    const int aidx = (p*64 + kc*32 + kg*8) ^ ((p&7)<<3);
    u16x8 au = *(const u16x8*)(&hbuf[wave][aidx]);
    bf16x8 ab = __builtin_bit_cast(bf16x8, au);
    #pragma unroll
    for (int tt=0; tt<4; ++tt){
      const int col = (lane&15) + (tt<<4);
      u16x8 bu = *(const u16x8*)(w2s + (col<<6) + ((((kc<<2)+kg) ^ (col&7))<<3));
      acc2[tt] = __builtin_amdgcn_mfma_f32_16x16x32_bf16(
          ab, __builtin_bit_cast(bf16x8, bu), acc2[tt], 0,0,0);
    }
  }
  // overwrite h1 with h2 in place: all h1 reads (above) precede these writes
  // in this wave's program order; LDS ops within a wave execute in order.
  #pragma unroll
  for (int tt=0; tt<4; ++tt){
    const int col = (lane&15) + (tt<<4);
    const float bias = b2[col];
    #pragma unroll
    for (int r=0; r<4; ++r){
      const int row = (kg<<2) + r;
      float v = acc2[tt][r] + bias;
      v = v > 0.f ? v : 0.f;
      hbuf[wave][(row*64 + col) ^ ((row&7)<<3)] = f2bf(v);
    }
  }

  // ---- layer 3: [16 x 64] @ [64 x 3] + sigmoid ----
  if (lane < 48){
    const int pp = lane / 3, c = lane % 3;
    float sum = b3[c];
    #pragma unroll
    for (int o=0; o<64; ++o){
      sum += bf2f(hbuf[wave][(pp*64+o) ^ ((pp&7)<<3)]) * W3[o*3+c];
    }
    const int gpp = (blockIdx.x << 7) + (wave << 4) + pp;
    color[(size_t)gpp*3 + c] = 1.f/(1.f+__expf(-sum));
  }
}

extern "C" void kernel_launch(void* const* d_in, const int* in_sizes, int n_in,
                              void* d_out, int out_size, void* d_ws, size_t ws_size,
                              hipStream_t stream){
  const float* xyz  = (const float*)d_in[0];
  const float* fg   = (const float*)d_in[1];
  const float* dens = (const float*)d_in[2];
  const float* W1   = (const float*)d_in[3];
  const float* b1   = (const float*)d_in[4];
  const float* W2   = (const float*)d_in[5];
  const float* b2   = (const float*)d_in[6];
  const float* W3   = (const float*)d_in[7];
  const float* b3   = (const float*)d_in[8];
  float* out = (float*)d_out;

  u16* W1T = (u16*)d_ws;            // 64*512*2 = 64 KiB
  u16* W2T = W1T + 64*512;          // 64*64*2  =  8 KiB

  hipLaunchKernelGGL(prep_weights, dim3(64), dim3(256), 0, stream, W1, W2, W1T, W2T);
  hipLaunchKernelGGL(density_sigmoid, dim3(DENS_N/1024), dim3(256), 0, stream,
                     (const float4*)dens, (float4*)out);
  hipLaunchKernelGGL(fused_mlp, dim3(NPTS/128), dim3(512), 0, stream,
                     xyz, fg, W1T, W2T, b1, b2, W3, b3, out + DENS_N);
}